// Round 12
// baseline (192.377 us; speedup 1.0000x reference)
//
#include <hip/hip_runtime.h>
#include <stdint.h>

typedef unsigned short u16;
typedef unsigned int u32;
typedef __bf16 bf16x8 __attribute__((ext_vector_type(8)));
typedef float f32x4 __attribute__((ext_vector_type(4)));

#define NH 12
#define HD 64
#define SEQ 512
#define BATCH 16
#define HID 768
#define SCALE_Q 0.03608439182435161f  // 768^-0.5

__device__ __forceinline__ u16 f2bf(float f) {
    u32 u = __builtin_bit_cast(u32, f);
    u32 r = (u + 0x7FFFu + ((u >> 16) & 1u)) >> 16;
    return (u16)r;
}
__device__ __forceinline__ float bf2f(u16 h) {
    return __builtin_bit_cast(float, (u32)h << 16);
}

// async global -> LDS, 16B per lane; lds dest = wave-uniform base + lane*16
__device__ __forceinline__ void gl2lds16(const u16* g, u16* lds_base) {
    __builtin_amdgcn_global_load_lds(
        (const __attribute__((address_space(1))) u32*)g,
        (__attribute__((address_space(3))) u32*)lds_base, 16, 0, 0);
}

// ---------------- fused fp32 -> bf16 convert (all 6 tensors, one launch) ----------------
#define NXB 6144   // NX/1024
#define NEB 4096   // NE/1024
#define NWB 576    // NW/1024
__global__ void cvt_all(const float* __restrict__ x, const float* __restrict__ eb,
                        const float* __restrict__ w0, const float* __restrict__ w1,
                        const float* __restrict__ w2, const float* __restrict__ w3,
                        u16* __restrict__ dst) {
    int b = blockIdx.x;
    const float* s; int sb;
    if (b < NXB) { s = x; sb = 0; }
    else if (b < NXB + NEB) { s = eb; sb = NXB; }
    else if (b < NXB + NEB + NWB) { s = w0; sb = NXB + NEB; }
    else if (b < NXB + NEB + 2 * NWB) { s = w1; sb = NXB + NEB + NWB; }
    else if (b < NXB + NEB + 3 * NWB) { s = w2; sb = NXB + NEB + 2 * NWB; }
    else { s = w3; sb = NXB + NEB + 3 * NWB; }
    int li = (b - sb) * 1024 + threadIdx.x * 4;
    float4 v = *(const float4*)(s + li);
    ushort4 o;
    o.x = f2bf(v.x); o.y = f2bf(v.y); o.z = f2bf(v.z); o.w = f2bf(v.w);
    *(ushort4*)(dst + (size_t)b * 1024 + threadIdx.x * 4) = o;
}

// ---------------- NT GEMM mainloop: 3-buffer ring, prefetch distance 2, counted vmcnt ----------------
__device__ __forceinline__ void stage_gemm(
    const u16* __restrict__ Ag, const u16* __restrict__ Bg, int k0,
    u16* As, u16* Bs, int r0, int q0, int r1, int q1, int w)
{
    gl2lds16(Ag + (size_t)r0 * HID + k0 + q0, As + w * 512);
    gl2lds16(Ag + (size_t)r1 * HID + k0 + q1, As + 2048 + w * 512);
    gl2lds16(Bg + (size_t)r0 * HID + k0 + q0, Bs + w * 512);
    gl2lds16(Bg + (size_t)r1 * HID + k0 + q1, Bs + 2048 + w * 512);
}

__device__ __forceinline__ void gemm_mainloop(
    const u16* __restrict__ Ag, const u16* __restrict__ Bg,
    u16 (*As)[128 * 32], u16 (*Bs)[128 * 32], f32x4 (&acc)[4][4])
{
    const int tid = threadIdx.x;
    const int l = tid & 63, w = tid >> 6;
    const int wm = w & 1, wn = w >> 1;
    const int lr = l & 15, lg = l >> 4;

    const int c0 = tid, c1 = tid + 256;
    const int r0 = c0 >> 2, q0 = (((c0 & 3) ^ ((r0 >> 1) & 3)) * 8);
    const int r1 = c1 >> 2, q1 = (((c1 & 3) ^ ((r1 >> 1) & 3)) * 8);

    const int sA = (lg ^ ((lr >> 1) & 3)) * 8;

    stage_gemm(Ag, Bg, 0, As[0], Bs[0], r0, q0, r1, q1, w);
    stage_gemm(Ag, Bg, 32, As[1], Bs[1], r0, q0, r1, q1, w);

    int cur = 0;
    for (int i = 0; i < 24; i++) {
        if (i < 23)
            asm volatile("s_waitcnt vmcnt(4) lgkmcnt(0)" ::: "memory");
        else
            asm volatile("s_waitcnt vmcnt(0) lgkmcnt(0)" ::: "memory");
        __builtin_amdgcn_s_barrier();
        __builtin_amdgcn_sched_barrier(0);

        int nxt = cur + 2; if (nxt >= 3) nxt -= 3;
        if (i < 22)
            stage_gemm(Ag, Bg, (i + 2) * 32, As[nxt], Bs[nxt], r0, q0, r1, q1, w);

        bf16x8 af[4], bfr[4];
#pragma unroll
        for (int mi = 0; mi < 4; mi++)
            af[mi] = *(const bf16x8*)(As[cur] + (wm * 64 + mi * 16 + lr) * 32 + sA);
#pragma unroll
        for (int ni = 0; ni < 4; ni++)
            bfr[ni] = *(const bf16x8*)(Bs[cur] + (wn * 64 + ni * 16 + lr) * 32 + sA);
#pragma unroll
        for (int mi = 0; mi < 4; mi++)
#pragma unroll
            for (int ni = 0; ni < 4; ni++)
                acc[mi][ni] = __builtin_amdgcn_mfma_f32_16x16x32_bf16(af[mi], bfr[ni], acc[mi][ni], 0, 0, 0);

        cur += 1; if (cur >= 3) cur -= 3;
    }
}

// ---------------- fused QKV GEMM: R1 mainloop + coalesced epilogues for Q/V AND K ----------------
// Q/V: acc -> swizzled LDS [d=128][n=128] -> 16B uint4 stores, 256B row segments (R11, verified).
// K:   acc -> swizzled LDS [n=128][d=128] (col ^ ((n&7)<<3), bits 3-5 disjoint from intra-16B
//      offset bits -> read/write bijective) -> 16B uint4 stores, full 128B head-rows.
__global__ __launch_bounds__(256, 3) void gemm_qkv(
    const u16* __restrict__ xb, const u16* __restrict__ wq,
    const u16* __restrict__ wk, const u16* __restrict__ wv,
    const float* __restrict__ bv,
    u16* __restrict__ qtb, u16* __restrict__ kb, u16* __restrict__ vtb)
{
    __shared__ __align__(16) u16 SH[6 * 4096];   // 48 KB: As = SH[0..3), Bs = SH[3..6) tiles
    u16 (*As)[128 * 32] = reinterpret_cast<u16 (*)[128 * 32]>(SH);
    u16 (*Bs)[128 * 32] = reinterpret_cast<u16 (*)[128 * 32]>(SH + 3 * 4096);
    const int tid = threadIdx.x;
    const int l = tid & 63, w = tid >> 6;
    const int wm = w & 1, wn = w >> 1;
    const int lr = l & 15, lg = l >> 4;
    const int mt = blockIdx.x, nt = blockIdx.y, z = blockIdx.z;

    const u16* Bw = (z == 0) ? wq : (z == 1) ? wk : wv;
    const u16* Ag = xb + (size_t)(mt * 128) * HID;
    const u16* Bg = Bw + (size_t)(nt * 128) * HID;

    f32x4 acc[4][4] = {};
    gemm_mainloop(Ag, Bg, As, Bs, acc);

    if (z == 1) {
        // K: [b,h,n,d] — transpose through LDS for 128B-coalesced row stores
        __syncthreads();                 // mainloop LDS reads complete before reuse
        u16* T = SH;                     // [n=128][d=128], col XOR-swizzled
#pragma unroll
        for (int mi = 0; mi < 4; mi++) {
#pragma unroll
            for (int ni = 0; ni < 4; ni++) {
                const int dcol = wn * 64 + ni * 16 + lr;
#pragma unroll
                for (int r2 = 0; r2 < 4; r2++) {
                    const int n = wm * 64 + mi * 16 + lg * 4 + r2;
                    T[n * 128 + (dcol ^ ((n & 7) << 3))] = f2bf(acc[mi][ni][r2]);
                }
            }
        }
        __syncthreads();
#pragma unroll
        for (int p = 0; p < 8; p++) {
            const int idx = p * 256 + tid;
            const int n = idx >> 4, c8 = (idx & 15) * 8;
            uint4 v = *(const uint4*)(T + n * 128 + (c8 ^ ((n & 7) << 3)));
            const int jg = nt * 128 + c8;
            const int h = jg >> 6, d = jg & 63;
            const int i0 = mt * 128 + n;
            const int b = i0 >> 9, n0 = i0 & 511;
            *(uint4*)(kb + ((size_t)(b * NH + h) * SEQ + n0) * HD + d) = v;
        }
    } else {
        // Q/V: [b,h,d,n] — transpose through LDS for coalesced stores (R11, verified)
        const float sc = (z == 0) ? SCALE_Q : 1.0f;
        __syncthreads();
        u16* T = SH;                     // 128 cols(d) x 128 rows(n) bf16 = 32 KB
#pragma unroll
        for (int mi = 0; mi < 4; mi++) {
#pragma unroll
            for (int ni = 0; ni < 4; ni++) {
                const int col = wn * 64 + ni * 16 + lr;          // d-local
                const int rowb = wm * 64 + mi * 16 + lg * 4;     // n-local
                float bb = (z == 2) ? bv[nt * 128 + col] : 0.0f;
                ushort4 pk;
                pk.x = f2bf(fmaf(acc[mi][ni][0], sc, bb));
                pk.y = f2bf(fmaf(acc[mi][ni][1], sc, bb));
                pk.z = f2bf(fmaf(acc[mi][ni][2], sc, bb));
                pk.w = f2bf(fmaf(acc[mi][ni][3], sc, bb));
                *(ushort4*)(T + col * 128 + (rowb ^ ((col & 7) << 4))) = pk;
            }
        }
        __syncthreads();
        const int b = mt >> 2, n0b = (mt & 3) * 128;
        u16* O = (z == 0) ? qtb : vtb;
#pragma unroll
        for (int p = 0; p < 8; p++) {
            const int idx = p * 256 + tid;
            const int col = idx >> 4, c = idx & 15;
            uint4 v = *(const uint4*)(T + col * 128 + ((c * 8) ^ ((col & 7) << 4)));
            const int jg = nt * 128 + col;
            const int h = jg >> 6, d = jg & 63;
            *(uint4*)(O + ((size_t)(b * NH + h) * HD + d) * SEQ + n0b + c * 8) = v;
        }
    }
}

// ---------------- output GEMM: fp32 out + bias (R2 XCD-chunked remap) ----------------
__global__ __launch_bounds__(256, 3) void gemm_out(
    const u16* __restrict__ A, const u16* __restrict__ wo,
    const float* __restrict__ bo, float* __restrict__ Cout)
{
    __shared__ __align__(16) u16 As[3][128 * 32];
    __shared__ __align__(16) u16 Bs[3][128 * 32];
    const int tid = threadIdx.x;
    const int l = tid & 63, w = tid >> 6;
    const int wm = w & 1, wn = w >> 1;
    const int lr = l & 15, lg = l >> 4;

    const int L = blockIdx.x;
    const int xcd = L & 7, s = L >> 3;
    const int nt = s >> 3;
    const int mt = xcd * 8 + (s & 7);

    const u16* Ag = A + (size_t)(mt * 128) * HID;
    const u16* Bg = wo + (size_t)(nt * 128) * HID;

    f32x4 acc[4][4] = {};
    gemm_mainloop(Ag, Bg, As, Bs, acc);

#pragma unroll
    for (int mi = 0; mi < 4; mi++) {
#pragma unroll
        for (int ni = 0; ni < 4; ni++) {
            const int jg = nt * 128 + wn * 64 + ni * 16 + lr;
            float bb = bo[jg];
#pragma unroll
            for (int r2 = 0; r2 < 4; r2++) {
                int ig = mt * 128 + wm * 64 + mi * 16 + lg * 4 + r2;
                Cout[(size_t)ig * HID + jg] = acc[mi][ni][r2] + bb;
            }
        }
    }
}

// ---------------- fused flash attention: R2 datapath, 2 Q-blocks per wave + coalesced stores ----------------
__device__ __forceinline__ void stage_kv(
    const u16* __restrict__ Kg, const u16* __restrict__ Vg, int mt0,
    u16* Ksb, u16* Vsb, int kr0, int kc0, int kr1, int kc1, int w)
{
    gl2lds16(Kg + (size_t)(mt0 + kr0) * HD + kc0 * 8, Ksb + w * 512);
    gl2lds16(Kg + (size_t)(mt0 + kr1) * HD + kc1 * 8, Ksb + 2048 + w * 512);
    gl2lds16(Vg + (size_t)kr0 * SEQ + mt0 + kc0 * 8, Vsb + w * 512);
    gl2lds16(Vg + (size_t)kr1 * SEQ + mt0 + kc1 * 8, Vsb + 2048 + w * 512);
}

__global__ __launch_bounds__(256, 3) void attn_kernel(
    const u16* __restrict__ qtb, const u16* __restrict__ kb, const u16* __restrict__ vtb,
    const u16* __restrict__ ebb, u16* __restrict__ ob)
{
    __shared__ __align__(16) u16 Ks[2][64 * 64];
    __shared__ __align__(16) u16 Vs[2][64 * 64];
    __shared__ __align__(16) u16 Ps[8][16 * 64];   // 2 slabs per wave (qb0: w, qb1: 4+w)

    const int tid = threadIdx.x;
    const int l = tid & 63, w = tid >> 6;
    const int lr = l & 15, lg = l >> 4;

    // XCD-aware decode: 768 blocks = 8 xcd * (2 b * 12 h * 4 qt); h outer, qt inner.
    const int L = blockIdx.x;
    const int xcd = L & 7, s = L >> 3;            // s in [0,96)
    const int b = xcd * 2 + (s / 48);
    const int s2 = s % 48;
    const int h = s2 >> 2, qt = s2 & 3;

    const int bh = b * NH + h;
    const int qrow0 = qt * 128 + w * 16;          // qb0 rows; qb1 = qrow0 + 64

    const u16* Kg = kb + (size_t)bh * SEQ * HD;
    const u16* Vg = vtb + (size_t)bh * HD * SEQ;
    const u16* Eg0 = ebb + ((size_t)b * SEQ + qrow0 + lg * 4) * SEQ;
    const u16* Eg1 = Eg0 + (size_t)64 * SEQ;

    // staging chunk assignment (swizzled): p = row*8 + (c ^ (row&7))
    const int p0 = tid, p1 = tid + 256;
    const int kr0 = p0 >> 3, kc0 = (p0 & 7) ^ (kr0 & 7);
    const int kr1 = p1 >> 3, kc1 = (p1 & 7) ^ (kr1 & 7);

    stage_kv(Kg, Vg, 0, Ks[0], Vs[0], kr0, kc0, kr1, kc1, w);

    // Q fragments (A-layout) gathered from transposed Q [b,h,d,n]; two q-blocks
    const u16* Qg = qtb + (size_t)bh * HD * SEQ + qrow0 + lr;
    bf16x8 qA0, qA1, qB0, qB1;
#pragma unroll
    for (int j = 0; j < 8; j++) {
        qA0[j] = __builtin_bit_cast(__bf16, Qg[(size_t)(lg * 8 + j) * SEQ]);
        qA1[j] = __builtin_bit_cast(__bf16, Qg[(size_t)(lg * 8 + j + 32) * SEQ]);
        qB0[j] = __builtin_bit_cast(__bf16, Qg[(size_t)(lg * 8 + j) * SEQ + 64]);
        qB1[j] = __builtin_bit_cast(__bf16, Qg[(size_t)(lg * 8 + j + 32) * SEQ + 64]);
    }

    bf16x8 ones;
#pragma unroll
    for (int j = 0; j < 8; j++) ones[j] = __builtin_bit_cast(__bf16, (u16)0x3F80);

    f32x4 oacc0[4] = {}, oacc1[4] = {};
    f32x4 lacc0 = {}, lacc1 = {};
    float amax0[4] = {0.f, 0.f, 0.f, 0.f};
    float amax1[4] = {0.f, 0.f, 0.f, 0.f};
    u16* Pw0 = Ps[w];
    u16* Pw1 = Ps[4 + w];

    for (int t = 0; t < 8; t++) {
        const int cur = t & 1;
        const int mt0 = t * 64;
        __syncthreads();  // drains tile-t loads; prev tile's reads done

        // bias loads FIRST (vmcnt-ordered before the prefetch below)
        u16 bl0[4][4], bl1[4][4];
#pragma unroll
        for (int mi = 0; mi < 4; mi++)
#pragma unroll
            for (int r = 0; r < 4; r++) {
                bl0[mi][r] = Eg0[(size_t)r * SEQ + mt0 + mi * 16 + lr];
                bl1[mi][r] = Eg1[(size_t)r * SEQ + mt0 + mi * 16 + lr];
            }

        if (t < 7)
            stage_kv(Kg, Vg, mt0 + 64, Ks[cur ^ 1], Vs[cur ^ 1], kr0, kc0, kr1, kc1, w);

        // S = (Q*scale) K^T + bias (bias as MFMA C-init); P = exp(S), no max.
        float sm0[4][4], sm1[4][4];
#pragma unroll
        for (int mi = 0; mi < 4; mi++) {
            const int row = mi * 16 + lr;
            bf16x8 kf0 = *(const bf16x8*)(Ks[cur] + row * 64 + ((lg ^ (row & 7)) * 8));
            bf16x8 kf1 = *(const bf16x8*)(Ks[cur] + row * 64 + (((4 + lg) ^ (row & 7)) * 8));
            f32x4 s0, s1;
#pragma unroll
            for (int r = 0; r < 4; r++) { s0[r] = bf2f(bl0[mi][r]); s1[r] = bf2f(bl1[mi][r]); }
            s0 = __builtin_amdgcn_mfma_f32_16x16x32_bf16(qA0, kf0, s0, 0, 0, 0);
            s0 = __builtin_amdgcn_mfma_f32_16x16x32_bf16(qA1, kf1, s0, 0, 0, 0);
            s1 = __builtin_amdgcn_mfma_f32_16x16x32_bf16(qB0, kf0, s1, 0, 0, 0);
            s1 = __builtin_amdgcn_mfma_f32_16x16x32_bf16(qB1, kf1, s1, 0, 0, 0);
#pragma unroll
            for (int r = 0; r < 4; r++) {
                float a = s0[r], c = s1[r];
                amax0[r] = fmaxf(amax0[r], fabsf(a));
                amax1[r] = fmaxf(amax1[r], fabsf(c));
                sm0[mi][r] = __expf(a);
                sm1[mi][r] = __expf(c);
            }
        }

        // P: C-layout -> per-wave swizzled LDS (two slabs) -> A-layout
#pragma unroll
        for (int mi = 0; mi < 4; mi++)
#pragma unroll
            for (int r = 0; r < 4; r++) {
                const int q = lg * 4 + r;
                const int chunk = mi * 2 + (lr >> 3);
                const int off = q * 64 + ((chunk ^ (q & 7)) * 8) + (lr & 7);
                Pw0[off] = f2bf(sm0[mi][r]);
                Pw1[off] = f2bf(sm1[mi][r]);
            }

        // PV: vf fragments read ONCE, feed both q-blocks.
#pragma unroll
        for (int ks = 0; ks < 2; ks++) {
            bf16x8 pf0 = *(const bf16x8*)(Pw0 + lr * 64 + (((ks * 4 + lg) ^ (lr & 7)) * 8));
            bf16x8 pf1 = *(const bf16x8*)(Pw1 + lr * 64 + (((ks * 4 + lg) ^ (lr & 7)) * 8));
#pragma unroll
            for (int di = 0; di < 4; di++) {
                const int row = di * 16 + lr;
                bf16x8 vf = *(const bf16x8*)(Vs[cur] + row * 64 + (((ks * 4 + lg) ^ (row & 7)) * 8));
                oacc0[di] = __builtin_amdgcn_mfma_f32_16x16x32_bf16(pf0, vf, oacc0[di], 0, 0, 0);
                oacc1[di] = __builtin_amdgcn_mfma_f32_16x16x32_bf16(pf1, vf, oacc1[di], 0, 0, 0);
            }
            lacc0 = __builtin_amdgcn_mfma_f32_16x16x32_bf16(pf0, ones, lacc0, 0, 0, 0);
            lacc1 = __builtin_amdgcn_mfma_f32_16x16x32_bf16(pf1, ones, lacc1, 0, 0, 0);
        }
    }

    // epilogue: per-wave LDS transpose into OWN Ps slabs (free after t-loop; no barrier
    // needed — same wave-ownership as during the loop), then 128B-row uint4 stores.
    // T layout: [n=16][d=64], col ^= ((n&7)<<3) (mask bits 3-5 disjoint from 16B-offset bits).
#pragma unroll
    for (int r = 0; r < 4; r++) {
        float am0 = amax0[r], am1 = amax1[r];
        am0 = fmaxf(am0, __shfl_xor(am0, 1));
        am0 = fmaxf(am0, __shfl_xor(am0, 2));
        am0 = fmaxf(am0, __shfl_xor(am0, 4));
        am0 = fmaxf(am0, __shfl_xor(am0, 8));
        am1 = fmaxf(am1, __shfl_xor(am1, 1));
        am1 = fmaxf(am1, __shfl_xor(am1, 2));
        am1 = fmaxf(am1, __shfl_xor(am1, 4));
        am1 = fmaxf(am1, __shfl_xor(am1, 8));
        float inv0 = (am0 > 0.f) ? (1.0f / lacc0[r]) : 0.0f;  // all-zero row -> 0 (ref: NaN->0)
        float inv1 = (am1 > 0.f) ? (1.0f / lacc1[r]) : 0.0f;
        const int n = lg * 4 + r;                              // n-local 0..15
#pragma unroll
        for (int di = 0; di < 4; di++) {
            const int sc_ = (di * 16 + lr) ^ ((n & 7) << 3);
            Pw0[n * 64 + sc_] = f2bf(oacc0[di][r] * inv0);
            Pw1[n * 64 + sc_] = f2bf(oacc1[di][r] * inv1);
        }
    }
    u16* obase = ob + ((size_t)b * SEQ + qrow0) * HID + h * HD;
#pragma unroll
    for (int p = 0; p < 2; p++) {
        const int idx = p * 64 + l;
        const int n = idx >> 3, c8 = (idx & 7) * 8;
        uint4 v0 = *(const uint4*)(Pw0 + n * 64 + (c8 ^ ((n & 7) << 3)));
        uint4 v1 = *(const uint4*)(Pw1 + n * 64 + (c8 ^ ((n & 7) << 3)));
        *(uint4*)(obase + (size_t)n * HID + c8) = v0;
        *(uint4*)(obase + (size_t)(n + 64) * HID + c8) = v1;
    }
}

// ---------------- launch ----------------
extern "C" void kernel_launch(void* const* d_in, const int* in_sizes, int n_in,
                              void* d_out, int out_size, void* d_ws, size_t ws_size,
                              hipStream_t stream) {
    (void)in_sizes; (void)n_in; (void)out_size; (void)ws_size;
    const float* x  = (const float*)d_in[0];
    const float* eb = (const float*)d_in[1];
    const float* Wq = (const float*)d_in[2];
    const float* Wk = (const float*)d_in[3];
    const float* Wv = (const float*)d_in[4];
    const float* bv = (const float*)d_in[5];
    const float* Wo = (const float*)d_in[6];
    const float* bo = (const float*)d_in[7];
    float* out = (float*)d_out;

    const int NX = BATCH * SEQ * HID;   // 6291456
    const int NW = HID * HID;           // 589824
    const int NE = BATCH * SEQ * SEQ;   // 4194304
    u16* ws   = (u16*)d_ws;
    u16* xb   = ws;                 // contiguous cvt region: [x | eb | wq | wk | wv | wo]
    u16* ebb  = xb + NX;
    u16* wqb  = ebb + NE;
    u16* wkb  = wqb + NW;
    u16* wvb  = wkb + NW;
    u16* wob  = wvb + NW;
    u16* qtb  = wob + NW;
    u16* kb   = qtb + NX;
    u16* vtb  = kb + NX;
    u16* obuf = vtb + NX;

    cvt_all<<<NXB + NEB + 4 * NWB, 256, 0, stream>>>(x, eb, Wq, Wk, Wv, Wo, ws);

    gemm_qkv<<<dim3(64, 6, 3), 256, 0, stream>>>(xb, wqb, wkb, wvb, bv, qtb, kb, vtb);

    attn_kernel<<<768, 256, 0, stream>>>(qtb, kb, vtb, ebb, obuf);

    gemm_out<<<384, 256, 0, stream>>>(obuf, wob, bo, out);
}